// Round 5
// baseline (123.496 us; speedup 1.0000x reference)
//
#include <hip/hip_runtime.h>
#include <math.h>

#define NN 50000
#define RR 8
#define EE 100000
#define BB 16384
#define ET 800000
#define ENDV 0xFFFFFFFFu

typedef unsigned int uint;
typedef unsigned short ushort;
typedef __attribute__((ext_vector_type(4))) float f32x4;
typedef _Float16 f16x8 __attribute__((ext_vector_type(8)));

// A16 planes (32768 rows x 128 fp16 each): 0=self_hi, 1=self_lo, 2+r=U_r
// Wfrag: [slot r(9)][plane hi/lo][nfg(8)][ks(4)][lane(64)][8 fp16]; slot 8 = self kernel

// =================== prep: edge linked-list + emb16 + W prepack + self hi/lo ===================
// grid 656 x 256. All blocks: edge pack. 0..390 emb16; 391..399 Wfrag; 400..655 self planes.
__global__ __launch_bounds__(256) void prep(
    const float* __restrict__ emb, const float* __restrict__ rel_k, const float* __restrict__ self_k,
    const float* __restrict__ head_e, const float* __restrict__ tail_e,
    const int* __restrict__ adj_rows, const int* __restrict__ adj_cols, const float* __restrict__ adj_vals,
    uint* __restrict__ head, uint2* __restrict__ epack,
    ushort* __restrict__ emb16, ushort* __restrict__ Wfrag, ushort* __restrict__ A16)
{
    const int tid = threadIdx.x, bid = blockIdx.x;

    // ---- edge pack: head[n*8+r] chain; epack[e] = {col<<16 | val_fp16, next} ----
    {
        int g = bid * 256 + tid;                  // < 167936
        #pragma unroll
        for (int ii = 0; ii < 5; ii++) {
            int e = g + ii * 167936;
            if (e < ET) {
                int r = e / EE;
                int row = adj_rows[e];
                ushort v16 = __builtin_bit_cast(ushort, (_Float16)adj_vals[e]);
                uint old = atomicExch(&head[row * 8 + r], (uint)e);
                epack[e] = make_uint2(((uint)adj_cols[e] << 16) | (uint)v16, old);
            }
        }
    }

    if (bid < 391) {
        // ---- emb -> fp16 ----
        #pragma unroll
        for (int i = 0; i < 16; i++) {
            int c = i * 256 + tid;
            int row = bid * 128 + (c >> 5);
            if (row < NN) {
                int k4 = (c & 31) * 4;
                float4 v = *(const float4*)(emb + (size_t)row * 128 + k4);
                _Float16 h4[4] = {(_Float16)v.x, (_Float16)v.y, (_Float16)v.z, (_Float16)v.w};
                *(ulonglong1*)(emb16 + (size_t)row * 128 + k4) =
                    *(ulonglong1*)h4;
            }
        }
    } else if (bid < 400) {
        // ---- W prepack (hi/lo fragment layout) ----
        int r = bid - 391;                        // 0..8 (8 = self)
        const float* src = (r < RR) ? rel_k + (size_t)r * 128 * 128 : self_k;
        __shared__ float tt[128][132];            // [n][k]
        for (int i = 0; i < 64; i++) {
            int idx = i * 256 + tid;              // coalesced read W[k][n]
            tt[idx & 127][idx >> 7] = src[idx];
        }
        __syncthreads();
        #pragma unroll
        for (int q = 0; q < 8; q++) {
            int ls = q * 256 + tid;
            int nfg = ls >> 8, ks = (ls >> 6) & 3, lane = ls & 63;
            int n = nfg * 16 + (lane & 15);
            int k0 = ks * 32 + (lane >> 4) * 8;
            f16x8 hi, lo;
            #pragma unroll
            for (int j = 0; j < 8; j++) {
                float x = tt[n][k0 + j];
                _Float16 h = (_Float16)x;
                hi[j] = h;
                lo[j] = (_Float16)(x - (float)h);
            }
            size_t bo = (size_t)(r * 2) * 16384 + (size_t)(nfg * 4 + ks) * 512 + (size_t)lane * 8;
            *(f16x8*)(Wfrag + bo)         = hi;
            *(f16x8*)(Wfrag + 16384 + bo) = lo;
        }
    } else {
        // ---- self planes: [head_e; tail_e] -> A16 plane0 (hi), plane1 (lo) ----
        int sb2 = bid - 400;                      // 0..255, 128 rows each
        #pragma unroll
        for (int i = 0; i < 8; i++) {
            int c = i * 256 + tid;                // 2048 chunks of 8 floats
            int row = sb2 * 128 + (c >> 4);
            int k8 = (c & 15) * 8;
            const float* src = (row < BB) ? head_e + (size_t)row * 128
                                          : tail_e + (size_t)(row - BB) * 128;
            float4 v0 = *(const float4*)(src + k8);
            float4 v1 = *(const float4*)(src + k8 + 4);
            float xs[8] = {v0.x, v0.y, v0.z, v0.w, v1.x, v1.y, v1.z, v1.w};
            f16x8 h, lo;
            #pragma unroll
            for (int j = 0; j < 8; j++) {
                _Float16 hh = (_Float16)xs[j];
                h[j] = hh;
                lo[j] = (_Float16)(xs[j] - (float)hh);
            }
            *(f16x8*)(A16 + (size_t)row * 128 + k8)            = h;
            *(f16x8*)(A16 + ((size_t)32768 + row) * 128 + k8)  = lo;
        }
    }
}

// =================== gatherU: one 16-lane group per (slot, r); no barriers, no cap ===================
// grid 16384 x 256: bid>>11 = r; 16 consecutive slots per block -> coalesced U writes.
__global__ __launch_bounds__(256, 8) void gatherU(
    const int* __restrict__ head_idx, const int* __restrict__ tail_idx,
    const uint* __restrict__ head, const uint2* __restrict__ epack,
    const ushort* __restrict__ emb16, ushort* __restrict__ A16)
{
    const int tid = threadIdx.x, bid = blockIdx.x;
    const int g16 = tid >> 4, l16 = tid & 15;
    const int r = bid >> 11;
    const int slot = (bid & 2047) * 16 + g16;
    int n = (slot < BB) ? head_idx[slot] : tail_idx[slot - BB];
    uint e = head[n * 8 + r];
    float a[8] = {0.f,0.f,0.f,0.f,0.f,0.f,0.f,0.f};
    while (e != ENDV) {
        uint2 p = epack[e];                                   // 8B broadcast across group
        float v = (float)__builtin_bit_cast(_Float16, (ushort)(p.x & 0xFFFFu));
        uint col = p.x >> 16;
        f16x8 em = *(const f16x8*)(emb16 + (size_t)col * 128 + l16 * 8);
        #pragma unroll
        for (int q = 0; q < 8; q++) a[q] = fmaf(v, (float)em[q], a[q]);
        e = p.y;
    }
    f16x8 uu;
    #pragma unroll
    for (int q = 0; q < 8; q++) uu[q] = (_Float16)a[q];
    *(f16x8*)(A16 + ((size_t)(2 + r) * 32768 + slot) * 128 + l16 * 8) = uu;
}

// =================== gemm: out = sigmoid(A16[32768 x 10*128] @ Wcat) ===================
// grid 512 x 256 (2 blocks/CU). Tile 64 rows x 128 cols; K = 10 super-blocks of 128.
// T14 reg-staged double-buffered LDS with T2 XOR swizzle; W frags from hot L2.
__global__ __launch_bounds__(256) void gemm(
    const ushort* __restrict__ A16, const ushort* __restrict__ Wfrag,
    float* __restrict__ out)
{
    __shared__ char sA[2][16384];
    const int tid = threadIdx.x, bid = blockIdx.x;
    const int w = tid >> 6, l = tid & 63;
    const int lr = l & 15, kq = l >> 4;
    const int m0 = (w >> 1) * 32;                 // wave M offset (2x2 wave grid)
    const int nfg0 = (w & 1) * 4;                 // wave N fragment-group offset

    f32x4 acc[2][4];
    #pragma unroll
    for (int a = 0; a < 2; a++)
        #pragma unroll
        for (int b = 0; b < 4; b++) acc[a][b] = (f32x4){0.f, 0.f, 0.f, 0.f};

    float4 pf0, pf1, pf2, pf3;
    const char* Abase = (const char*)A16 + (size_t)bid * 64 * 256;

    #define STAGE(sb) {                                                         \
        const char* gp = Abase + (size_t)(sb) * 32768 * 256;                    \
        pf0 = *(const float4*)(gp + (0 * 256 + tid) * 16);                      \
        pf1 = *(const float4*)(gp + (1 * 256 + tid) * 16);                      \
        pf2 = *(const float4*)(gp + (2 * 256 + tid) * 16);                      \
        pf3 = *(const float4*)(gp + (3 * 256 + tid) * 16);                      \
    }
    #define WRITE(buf) {                                                        \
        _Pragma("unroll")                                                       \
        for (int i = 0; i < 4; i++) {                                           \
            int c = i * 256 + tid;                                              \
            int row = c >> 4, cc = c & 15;                                      \
            int off = row * 256 + ((cc * 16) ^ ((row & 7) << 4));               \
            *(float4*)(sA[buf] + off) = (i==0)?pf0:(i==1)?pf1:(i==2)?pf2:pf3;   \
        }                                                                       \
    }

    STAGE(0); WRITE(0); __syncthreads();

    for (int sb = 0; sb < 10; sb++) {
        if (sb < 9) STAGE(sb + 1);                // issue next loads early (T14)
        int wsl = (sb <= 1) ? 8 : sb - 2;
        const ushort* Wb = Wfrag + (size_t)wsl * 32768;
        const char* bufp = sA[sb & 1];
        #pragma unroll
        for (int ks = 0; ks < 4; ks++) {
            int kb = ks * 64 + kq * 16;
            f16x8 av[2];
            #pragma unroll
            for (int mf = 0; mf < 2; mf++) {
                int row = m0 + mf * 16 + lr;
                av[mf] = *(const f16x8*)(bufp + row * 256 + (kb ^ ((row & 7) << 4)));
            }
            f16x8 bh[4], bl[4];
            #pragma unroll
            for (int nf = 0; nf < 4; nf++) {
                size_t bo = (size_t)(((nfg0 + nf) * 4 + ks) * 64 + l) * 8;
                bh[nf] = *(const f16x8*)(Wb + bo);
                bl[nf] = *(const f16x8*)(Wb + 16384 + bo);
            }
            #pragma unroll
            for (int mf = 0; mf < 2; mf++)
                #pragma unroll
                for (int nf = 0; nf < 4; nf++) {
                    acc[mf][nf] = __builtin_amdgcn_mfma_f32_16x16x32_f16(av[mf], bh[nf], acc[mf][nf], 0, 0, 0);
                    if (sb != 1)   // self_lo plane pairs only with W_hi
                        acc[mf][nf] = __builtin_amdgcn_mfma_f32_16x16x32_f16(av[mf], bl[nf], acc[mf][nf], 0, 0, 0);
                }
        }
        __syncthreads();
        if (sb < 9) { WRITE((sb + 1) & 1); __syncthreads(); }
    }

    // ---- epilogue: sigmoid + store (D: col = nf*16+lr, row = kq*4+j) ----
    #pragma unroll
    for (int mf = 0; mf < 2; mf++)
        #pragma unroll
        for (int j = 0; j < 4; j++) {
            int lrow = m0 + mf * 16 + kq * 4 + j;
            size_t slot = (size_t)bid * 64 + lrow;
            #pragma unroll
            for (int nf = 0; nf < 4; nf++) {
                int col = (w & 1) * 64 + nf * 16 + lr;
                float x = acc[mf][nf][j];
                out[slot * 128 + col] = 1.f / (1.f + __expf(-x));
            }
        }
    #undef STAGE
    #undef WRITE
}

extern "C" void kernel_launch(void* const* d_in, const int* in_sizes, int n_in,
                              void* d_out, int out_size, void* d_ws, size_t ws_size,
                              hipStream_t stream)
{
    const float* embeddings = (const float*)d_in[0];
    const int*   head_idx   = (const int*)d_in[1];
    const float* head_e     = (const float*)d_in[2];
    const int*   tail_idx   = (const int*)d_in[3];
    const float* tail_e     = (const float*)d_in[4];
    const int*   adj_rows   = (const int*)d_in[5];
    const int*   adj_cols   = (const int*)d_in[6];
    const float* adj_vals   = (const float*)d_in[7];
    const float* rel_k      = (const float*)d_in[8];
    const float* self_k     = (const float*)d_in[9];
    float* out = (float*)d_out;

    // workspace layout (~105.3 MB)
    char* ws = (char*)d_ws;
    uint*   head  = (uint*)ws;                        //  1,600,000 B
    ushort* Wfrag = (ushort*)(ws + 1600512);          //    589,824 B
    ushort* emb16 = (ushort*)(ws + 2190336);          // 12,800,000 B
    uint2*  epack = (uint2*)(ws + 14990336);          //  6,400,000 B
    ushort* A16   = (ushort*)(ws + 21390336);         // 83,886,080 B (10 planes x 32768 x 128)

    hipMemsetAsync(head, 0xFF, (size_t)NN * 8 * 4, stream);

    prep<<<656, 256, 0, stream>>>(embeddings, rel_k, self_k, head_e, tail_e,
                                  adj_rows, adj_cols, adj_vals,
                                  head, epack, emb16, Wfrag, A16);

    gatherU<<<16384, 256, 0, stream>>>(head_idx, tail_idx, head, epack, emb16, A16);

    gemm<<<512, 256, 0, stream>>>(A16, Wfrag, out);
}